// Round 2
// baseline (1153.608 us; speedup 1.0000x reference)
//
#include <hip/hip_runtime.h>

#define DI __device__ __forceinline__

typedef unsigned int uint;
typedef unsigned short ushort;
typedef _Float16 half2t __attribute__((ext_vector_type(2)));

#define VOCAB 50257
#define NEMB 48
#define HID 128
#define G4 512
#define NCLS 2000
#define BATCH 512
#define SEQ 1024

#if __has_builtin(__builtin_amdgcn_fdot2)
DI float fdot2(half2t a, half2t b, float c) { return __builtin_amdgcn_fdot2(a, b, c, false); }
#else
DI float fdot2(half2t a, half2t b, float c) { return c + (float)a.x * (float)b.x + (float)a.y * (float)b.y; }
#endif

DI float sigm(float x) {
  // 1/(1+2^(-x*log2e)); v_exp/v_rcp ~1ulp, saturates correctly at +-inf
  return __builtin_amdgcn_rcpf(1.0f + __builtin_amdgcn_exp2f(-1.4426950408889634f * x));
}
DI float tanhfast(float x) {
  // 1 - 2/(2^(2x*log2e)+1); exact limits at +-1
  return 1.0f - 2.0f * __builtin_amdgcn_rcpf(__builtin_amdgcn_exp2f(2.8853900817779268f * x) + 1.0f);
}

// ---------------------------------------------------------------------------
// Phase A: P[v][j] = emb[v] . w_ih[j] + b_ih[j] + b_hh[j]  (fp32 math, f16 out)
// 32 vocab rows per 512-thread block; thread j owns gate column j.
// eL in LDS read as float4 broadcasts (all lanes same addr -> conflict-free).
// ---------------------------------------------------------------------------
#define VROWS 32
__global__ __launch_bounds__(512) void build_P(
    const float* __restrict__ emb, const float* __restrict__ w_ih,
    const float* __restrict__ b_ih, const float* __restrict__ b_hh,
    _Float16* __restrict__ P)
{
  __shared__ __align__(16) float eL[VROWS][NEMB];
  const int tid = threadIdx.x;
  const int v0 = blockIdx.x * VROWS;
  int nrows = VOCAB - v0; if (nrows > VROWS) nrows = VROWS;

  for (int f = tid; f < nrows * NEMB; f += 512)
    eL[f / NEMB][f % NEMB] = emb[(size_t)v0 * NEMB + f];

  float w[NEMB];
  {
    const float* wr = w_ih + (size_t)tid * NEMB;
#pragma unroll
    for (int k = 0; k < NEMB; k++) w[k] = wr[k];
  }
  float bias = b_ih[tid] + b_hh[tid];
  __syncthreads();

  for (int v = 0; v < nrows; v++) {
    const float4* e4 = (const float4*)&eL[v][0];
    float a = bias;
#pragma unroll
    for (int k = 0; k < NEMB / 4; k++) {
      float4 e = e4[k];
      a += w[4 * k] * e.x + w[4 * k + 1] * e.y + w[4 * k + 2] * e.z + w[4 * k + 3] * e.w;
    }
    P[(size_t)(v0 + v) * G4 + tid] = (_Float16)a;
  }
}

// ---------------------------------------------------------------------------
// Phase B: persistent LSTM scan. One block = 2 batch rows, 512 threads,
// thread j owns gate column j (W_hh row j converted to 64 half2 VGPRs).
// Per step: g = xg (P-gather prefetched 2 steps ahead) + h @ W_hh^T via
// v_dot2_f32_f16 (fp32 accum); gates by threads 0..255 (c in VGPR, h
// round-trips LDS as f16). Fused fp32 FC epilogue at t=1023.
// ---------------------------------------------------------------------------
template<bool USE_P>
__global__ __launch_bounds__(512, 2) void lstm_fused(
    const int* __restrict__ x, const float* __restrict__ emb,
    const float* __restrict__ w_ih, const float* __restrict__ w_hh,
    const float* __restrict__ b_ih, const float* __restrict__ b_hh,
    const float* __restrict__ w_fc, const float* __restrict__ b_fc,
    const _Float16* __restrict__ P, float* __restrict__ out)
{
  __shared__ int tokL[2 * SEQ];
  __shared__ __align__(16) _Float16 h16[2][HID];
  __shared__ __align__(8) half2t e16[2][2][NEMB / 2];
  __shared__ float g32[2][G4];
  __shared__ float h32[2][HID];

  const int tid = threadIdx.x;
  const int b0 = blockIdx.x * 2;

  { // both token rows are contiguous in x
    const int* xp = x + (size_t)b0 * SEQ;
#pragma unroll
    for (int i = 0; i < 4; i++) tokL[tid + 512 * i] = xp[tid + 512 * i];
  }

  half2t whh[HID / 2];
  {
    const float4* wr = (const float4*)(w_hh + (size_t)tid * HID);
#pragma unroll
    for (int k = 0; k < HID / 4; k++) {
      float4 wv = wr[k];
      half2t p0, p1;
      p0.x = (_Float16)wv.x; p0.y = (_Float16)wv.y;
      p1.x = (_Float16)wv.z; p1.y = (_Float16)wv.w;
      whh[2 * k] = p0; whh[2 * k + 1] = p1;
    }
  }
  half2t wih[NEMB / 2];
  float biasj = 0.0f;
  if (!USE_P) {
    const float* wr = w_ih + (size_t)tid * NEMB;
#pragma unroll
    for (int k = 0; k < NEMB / 2; k++) {
      half2t p; p.x = (_Float16)wr[2 * k]; p.y = (_Float16)wr[2 * k + 1];
      wih[k] = p;
    }
    biasj = b_ih[tid] + b_hh[tid];
  }
  if (tid < HID) { h16[0][tid] = (_Float16)0.0f; h16[1][tid] = (_Float16)0.0f; }
  __syncthreads(); // tokens + h16 visible

  float c = 0.0f;
  _Float16 pA0{}, pA1{}, pB0{}, pB1{};
  float2 einfl = {0.0f, 0.0f};
  int lb = 0, lk = 0;
  if (USE_P) {
    pA0 = P[(size_t)tokL[0] * G4 + tid];
    pA1 = P[(size_t)tokL[SEQ] * G4 + tid];
    pB0 = P[(size_t)tokL[1] * G4 + tid];
    pB1 = P[(size_t)tokL[SEQ + 1] * G4 + tid];
  } else {
    if (tid < NEMB) { // 48 loader lanes in wave 0; lane owns half2 slot lk of row lb
      lb = (tid >= NEMB / 2) ? 1 : 0;
      lk = tid - lb * (NEMB / 2);
      const float2* ep0 = (const float2*)(emb + (size_t)tokL[lb * SEQ + 0] * NEMB);
      const float2* ep1 = (const float2*)(emb + (size_t)tokL[lb * SEQ + 1] * NEMB);
      float2 e0 = ep0[lk];
      einfl = ep1[lk];
      half2t p; p.x = (_Float16)e0.x; p.y = (_Float16)e0.y;
      e16[0][lb][lk] = p;
    }
  }
  __syncthreads();

// One timestep; `par` is a 0/1 literal so all register-array indexing folds.
#define STEP(t, par) do {                                                      \
    int tc = (t) + 2; if (tc > SEQ - 1) tc = SEQ - 1;                          \
    float xg0, xg1;                                                            \
    if (USE_P) {                                                               \
      int tn0 = tokL[tc], tn1 = tokL[SEQ + tc];                                \
      xg0 = (float)((par) == 0 ? pA0 : pB0);                                   \
      xg1 = (float)((par) == 0 ? pA1 : pB1);                                   \
      _Float16 n0 = P[(size_t)tn0 * G4 + tid];  /* prefetch t+2 */             \
      _Float16 n1 = P[(size_t)tn1 * G4 + tid];                                 \
      if ((par) == 0) { pA0 = n0; pA1 = n1; } else { pB0 = n0; pB1 = n1; }     \
    } else {                                                                   \
      if (tid < NEMB) {                                                        \
        half2t p; p.x = (_Float16)einfl.x; p.y = (_Float16)einfl.y;            \
        e16[((t) + 1) & 1][lb][lk] = p; /* stage e for t+1 */                  \
        einfl = ((const float2*)(emb + (size_t)tokL[lb * SEQ + tc] * NEMB))[lk];\
      }                                                                        \
      xg0 = biasj; xg1 = biasj;                                                \
      _Pragma("unroll")                                                        \
      for (int k = 0; k < NEMB / 2; k++) {                                     \
        xg0 = fdot2(wih[k], e16[(par)][0][k], xg0);                            \
        xg1 = fdot2(wih[k], e16[(par)][1][k], xg1);                            \
      }                                                                        \
    }                                                                          \
    const half2t* hp0 = (const half2t*)&h16[0][0];                             \
    const half2t* hp1 = (const half2t*)&h16[1][0];                             \
    float s00 = xg0, s01 = 0.0f, s10 = xg1, s11 = 0.0f;                        \
    _Pragma("unroll")                                                          \
    for (int k = 0; k < HID / 2; k += 2) {                                     \
      s00 = fdot2(whh[k],     hp0[k],     s00);                                \
      s01 = fdot2(whh[k + 1], hp0[k + 1], s01);                                \
      s10 = fdot2(whh[k],     hp1[k],     s10);                                \
      s11 = fdot2(whh[k + 1], hp1[k + 1], s11);                                \
    }                                                                          \
    g32[0][tid] = s00 + s01;                                                   \
    g32[1][tid] = s10 + s11;                                                   \
    __syncthreads();                                                           \
    if (tid < 2 * HID) {                                                       \
      int bb = tid >> 7, u = tid & (HID - 1);                                  \
      float gi = g32[bb][u],           gf = g32[bb][HID + u];                  \
      float gc = g32[bb][2 * HID + u], go = g32[bb][3 * HID + u];              \
      float fi = sigm(gi), ff = sigm(gf), gt = tanhfast(gc), fo = sigm(go);    \
      c = ff * c + fi * gt;                                                    \
      float hh = fo * tanhfast(c);                                             \
      h16[bb][u] = (_Float16)hh;                                               \
      if ((t) == SEQ - 1) h32[bb][u] = hh;                                     \
    }                                                                          \
    __syncthreads();                                                           \
  } while (0)

  for (int t = 0; t < SEQ; t += 2) { STEP(t, 0); STEP(t + 1, 1); }
#undef STEP

  // FC epilogue: out[b, n] = h32[b] . w_fc[n] + b_fc[n], fp32
#pragma unroll
  for (int kk = 0; kk < 4; kk++) {
    int n = tid + 512 * kk;
    if (n < NCLS) {
      const float4* wr = (const float4*)(w_fc + (size_t)n * HID);
      float bias = b_fc[n];
      float a0 = bias, a1 = bias;
#pragma unroll
      for (int k = 0; k < HID / 4; k++) {
        float4 wv = wr[k];
        a0 += h32[0][4 * k] * wv.x + h32[0][4 * k + 1] * wv.y
            + h32[0][4 * k + 2] * wv.z + h32[0][4 * k + 3] * wv.w;
        a1 += h32[1][4 * k] * wv.x + h32[1][4 * k + 1] * wv.y
            + h32[1][4 * k + 2] * wv.z + h32[1][4 * k + 3] * wv.w;
      }
      out[(size_t)b0 * NCLS + n] = a0;
      out[(size_t)(b0 + 1) * NCLS + n] = a1;
    }
  }
}

extern "C" void kernel_launch(void* const* d_in, const int* in_sizes, int n_in,
                              void* d_out, int out_size, void* d_ws, size_t ws_size,
                              hipStream_t stream) {
  const int*   xx   = (const int*)d_in[0];
  const float* emb  = (const float*)d_in[1];
  const float* w_ih = (const float*)d_in[2];
  const float* w_hh = (const float*)d_in[3];
  const float* b_ih = (const float*)d_in[4];
  const float* b_hh = (const float*)d_in[5];
  const float* w_fc = (const float*)d_in[6];
  const float* b_fc = (const float*)d_in[7];
  float* out = (float*)d_out;

  const size_t pbytes = (size_t)VOCAB * G4 * sizeof(_Float16); // 51.5 MB
  if (ws_size >= pbytes) {
    _Float16* P = (_Float16*)d_ws;
    build_P<<<(VOCAB + VROWS - 1) / VROWS, 512, 0, stream>>>(emb, w_ih, b_ih, b_hh, P);
    lstm_fused<true><<<BATCH / 2, 512, 0, stream>>>(xx, emb, w_ih, w_hh, b_ih, b_hh,
                                                    w_fc, b_fc, P, out);
  } else {
    lstm_fused<false><<<BATCH / 2, 512, 0, stream>>>(xx, emb, w_ih, w_hh, b_ih, b_hh,
                                                     w_fc, b_fc, (const _Float16*)nullptr, out);
  }
}

// Round 3
// 1003.403 us; speedup vs baseline: 1.1497x; 1.1497x over previous
//
#include <hip/hip_runtime.h>

#define DI __device__ __forceinline__

typedef unsigned int uint;
typedef unsigned short ushort;
typedef _Float16 half2t __attribute__((ext_vector_type(2)));

#define VOCAB 50257
#define NEMB 48
#define HID 128
#define G4 512
#define NCLS 2000
#define BATCH 512
#define SEQ 1024

#if __has_builtin(__builtin_amdgcn_fdot2)
DI float fdot2(half2t a, half2t b, float c) { return __builtin_amdgcn_fdot2(a, b, c, false); }
#else
DI float fdot2(half2t a, half2t b, float c) { return c + (float)a.x * (float)b.x + (float)a.y * (float)b.y; }
#endif

DI float sigm(float x) {
  return __builtin_amdgcn_rcpf(1.0f + __builtin_amdgcn_exp2f(-1.4426950408889634f * x));
}
DI float tanhfast(float x) {
  return 1.0f - 2.0f * __builtin_amdgcn_rcpf(__builtin_amdgcn_exp2f(2.8853900817779268f * x) + 1.0f);
}

// ---------------------------------------------------------------------------
// Phase A: P[v][j] = emb[v] . w_ih[j] + b_ih[j] + b_hh[j]  (fp32 math, f16 out)
// ---------------------------------------------------------------------------
#define VROWS 32
__global__ __launch_bounds__(512) void build_P(
    const float* __restrict__ emb, const float* __restrict__ w_ih,
    const float* __restrict__ b_ih, const float* __restrict__ b_hh,
    _Float16* __restrict__ P)
{
  __shared__ __align__(16) float eL[VROWS][NEMB];
  const int tid = threadIdx.x;
  const int v0 = blockIdx.x * VROWS;
  int nrows = VOCAB - v0; if (nrows > VROWS) nrows = VROWS;

  for (int f = tid; f < nrows * NEMB; f += 512)
    eL[f / NEMB][f % NEMB] = emb[(size_t)v0 * NEMB + f];

  float w[NEMB];
  {
    const float* wr = w_ih + (size_t)tid * NEMB;
#pragma unroll
    for (int k = 0; k < NEMB; k++) w[k] = wr[k];
  }
  float bias = b_ih[tid] + b_hh[tid];
  __syncthreads();

  for (int v = 0; v < nrows; v++) {
    const float4* e4 = (const float4*)&eL[v][0];
    float a = bias;
#pragma unroll
    for (int k = 0; k < NEMB / 4; k++) {
      float4 e = e4[k];
      a += w[4 * k] * e.x + w[4 * k + 1] * e.y + w[4 * k + 2] * e.z + w[4 * k + 3] * e.w;
    }
    P[(size_t)(v0 + v) * G4 + tid] = (_Float16)a;
  }
}

// ---------------------------------------------------------------------------
// Phase B: persistent LSTM scan. 512 blocks x 256 threads, ONE batch row per
// block (2 independent blocks/CU -> phase overlap). Thread j owns gate cols
// j and j+256; h row read once per thread (16 ds_read_b128 broadcast) and
// reused for both columns. Writes final h (f32) to hout.
// ---------------------------------------------------------------------------
template<bool USE_P>
__global__ __launch_bounds__(256, 2) void lstm_scan(
    const int* __restrict__ x, const float* __restrict__ emb,
    const float* __restrict__ w_ih, const float* __restrict__ w_hh,
    const float* __restrict__ b_ih, const float* __restrict__ b_hh,
    const _Float16* __restrict__ P, float* __restrict__ hout)
{
  __shared__ int tokL[SEQ];
  __shared__ __align__(16) _Float16 h16[HID];
  __shared__ float g32[G4];
  __shared__ __align__(8) half2t e16[2][NEMB / 2];

  const int tid = threadIdx.x;
  const int b = blockIdx.x;

  {
    const int* xp = x + (size_t)b * SEQ;
#pragma unroll
    for (int i = 0; i < SEQ / 256; i++) tokL[tid + 256 * i] = xp[tid + 256 * i];
  }

  // W_hh rows for cols tid and tid+256, converted to f16 pairs (128 VGPRs)
  half2t w0[HID / 2], w1[HID / 2];
  {
    const float4* wr0 = (const float4*)(w_hh + (size_t)tid * HID);
    const float4* wr1 = (const float4*)(w_hh + (size_t)(tid + 256) * HID);
#pragma unroll
    for (int k = 0; k < HID / 4; k++) {
      float4 a = wr0[k];
      half2t p; p.x = (_Float16)a.x; p.y = (_Float16)a.y; w0[2 * k] = p;
      p.x = (_Float16)a.z; p.y = (_Float16)a.w; w0[2 * k + 1] = p;
      float4 bv = wr1[k];
      p.x = (_Float16)bv.x; p.y = (_Float16)bv.y; w1[2 * k] = p;
      p.x = (_Float16)bv.z; p.y = (_Float16)bv.w; w1[2 * k + 1] = p;
    }
  }
  half2t wih0[NEMB / 2], wih1[NEMB / 2];
  float bias0 = 0.0f, bias1 = 0.0f;
  if (!USE_P) {
    const float* wr0 = w_ih + (size_t)tid * NEMB;
    const float* wr1 = w_ih + (size_t)(tid + 256) * NEMB;
#pragma unroll
    for (int k = 0; k < NEMB / 2; k++) {
      half2t p;
      p.x = (_Float16)wr0[2 * k]; p.y = (_Float16)wr0[2 * k + 1]; wih0[k] = p;
      p.x = (_Float16)wr1[2 * k]; p.y = (_Float16)wr1[2 * k + 1]; wih1[k] = p;
    }
    bias0 = b_ih[tid] + b_hh[tid];
    bias1 = b_ih[tid + 256] + b_hh[tid + 256];
  }
  if (tid < HID) h16[tid] = (_Float16)0.0f;
  __syncthreads(); // tokens + h16 visible

  float c = 0.0f;
  _Float16 pa0{}, pa1{}, pb0{}, pb1{};
  float2 einfl = {0.0f, 0.0f};
  if (USE_P) {
    const _Float16* r0 = P + (size_t)tokL[0] * G4;
    const _Float16* r1 = P + (size_t)tokL[1] * G4;
    pa0 = r0[tid]; pa1 = r0[tid + 256];
    pb0 = r1[tid]; pb1 = r1[tid + 256];
  } else {
    if (tid < NEMB / 2) {
      float2 e0 = ((const float2*)(emb + (size_t)tokL[0] * NEMB))[tid];
      einfl    = ((const float2*)(emb + (size_t)tokL[1] * NEMB))[tid];
      half2t p; p.x = (_Float16)e0.x; p.y = (_Float16)e0.y;
      e16[0][tid] = p;
    }
  }
  __syncthreads(); // e16[0] visible (no-op cost for USE_P)

#define STEP(t, par) do {                                                      \
    int tc = (t) + 2; if (tc > SEQ - 1) tc = SEQ - 1;                          \
    float xg0, xg1;                                                            \
    if (USE_P) {                                                               \
      xg0 = (float)((par) ? pb0 : pa0);                                        \
      xg1 = (float)((par) ? pb1 : pa1);                                        \
      const _Float16* rn = P + (size_t)tokL[tc] * G4; /* prefetch t+2 */       \
      _Float16 n0 = rn[tid], n1 = rn[tid + 256];                               \
      if ((par) == 0) { pa0 = n0; pa1 = n1; } else { pb0 = n0; pb1 = n1; }     \
    } else {                                                                   \
      if (tid < NEMB / 2) {                                                    \
        half2t p; p.x = (_Float16)einfl.x; p.y = (_Float16)einfl.y;            \
        e16[((t) + 1) & 1][tid] = p;                                           \
        einfl = ((const float2*)(emb + (size_t)tokL[tc] * NEMB))[tid];         \
      }                                                                        \
      xg0 = bias0; xg1 = bias1;                                                \
      _Pragma("unroll")                                                        \
      for (int k = 0; k < NEMB / 2; k++) {                                     \
        xg0 = fdot2(wih0[k], e16[(par)][k], xg0);                              \
        xg1 = fdot2(wih1[k], e16[(par)][k], xg1);                              \
      }                                                                        \
    }                                                                          \
    const uint4* hv = (const uint4*)h16;                                       \
    float s0 = xg0, u0 = 0.0f, s1 = xg1, u1 = 0.0f;                            \
    _Pragma("unroll")                                                          \
    for (int kt = 0; kt < HID / 8; kt++) {                                     \
      uint4 hq = hv[kt];                                                       \
      half2t ha = __builtin_bit_cast(half2t, hq.x);                            \
      half2t hb = __builtin_bit_cast(half2t, hq.y);                            \
      half2t hc = __builtin_bit_cast(half2t, hq.z);                            \
      half2t hd = __builtin_bit_cast(half2t, hq.w);                            \
      s0 = fdot2(w0[4 * kt + 0], ha, s0);                                      \
      u0 = fdot2(w0[4 * kt + 1], hb, u0);                                      \
      s0 = fdot2(w0[4 * kt + 2], hc, s0);                                      \
      u0 = fdot2(w0[4 * kt + 3], hd, u0);                                      \
      s1 = fdot2(w1[4 * kt + 0], ha, s1);                                      \
      u1 = fdot2(w1[4 * kt + 1], hb, u1);                                      \
      s1 = fdot2(w1[4 * kt + 2], hc, s1);                                      \
      u1 = fdot2(w1[4 * kt + 3], hd, u1);                                      \
    }                                                                          \
    g32[tid] = s0 + u0;                                                        \
    g32[tid + 256] = s1 + u1;                                                  \
    __syncthreads();                                                           \
    if (tid < HID) {                                                           \
      float gi = g32[tid],           gf = g32[HID + tid];                      \
      float gc = g32[2 * HID + tid], go = g32[3 * HID + tid];                  \
      float fi = sigm(gi), ff = sigm(gf), gt = tanhfast(gc), fo = sigm(go);    \
      c = ff * c + fi * gt;                                                    \
      float hh = fo * tanhfast(c);                                             \
      h16[tid] = (_Float16)hh;                                                 \
      if ((t) == SEQ - 1) hout[(size_t)b * HID + tid] = hh;                    \
    }                                                                          \
    __syncthreads();                                                           \
  } while (0)

  for (int t = 0; t < SEQ; t += 2) { STEP(t, 0); STEP(t + 1, 1); }
#undef STEP
}

// ---------------------------------------------------------------------------
// Phase C: FC  out[512,2000] = h[512,128] @ w_fc^T + b_fc.  64x64 tiles,
// K=128 staged transposed in LDS, 4x4 register blocking per thread.
// ---------------------------------------------------------------------------
#define FCR 64
#define FCC 64
__global__ __launch_bounds__(256) void fc_kernel(
    const float* __restrict__ h, const float* __restrict__ w_fc,
    const float* __restrict__ b_fc, float* __restrict__ out)
{
  __shared__ float aT[HID][FCR];
  __shared__ float bT[HID][FCC];
  const int tid = threadIdx.x;
  const int r0 = blockIdx.y * FCR;
  const int c0 = blockIdx.x * FCC;

  for (int f = tid; f < FCR * (HID / 4); f += 256) {
    int row = f >> 5, q = f & 31;
    float4 v = ((const float4*)h)[(((size_t)(r0 + row)) << 5) + q];
    aT[4 * q + 0][row] = v.x; aT[4 * q + 1][row] = v.y;
    aT[4 * q + 2][row] = v.z; aT[4 * q + 3][row] = v.w;
    int wrow = c0 + row;
    float4 wv;
    if (wrow < NCLS) wv = ((const float4*)w_fc)[(((size_t)wrow) << 5) + q];
    else { wv.x = 0.f; wv.y = 0.f; wv.z = 0.f; wv.w = 0.f; }
    bT[4 * q + 0][row] = wv.x; bT[4 * q + 1][row] = wv.y;
    bT[4 * q + 2][row] = wv.z; bT[4 * q + 3][row] = wv.w;
  }
  __syncthreads();

  const int cr = tid & 15, rr = tid >> 4;
  float acc[4][4];
#pragma unroll
  for (int i = 0; i < 4; i++)
#pragma unroll
    for (int j = 0; j < 4; j++) acc[i][j] = 0.0f;

#pragma unroll 4
  for (int k = 0; k < HID; k++) {
    float4 av = *(const float4*)&aT[k][4 * rr];
    float4 bv = *(const float4*)&bT[k][4 * cr];
    float a[4] = {av.x, av.y, av.z, av.w};
    float bb[4] = {bv.x, bv.y, bv.z, bv.w};
#pragma unroll
    for (int i = 0; i < 4; i++)
#pragma unroll
      for (int j = 0; j < 4; j++) acc[i][j] += a[i] * bb[j];
  }

#pragma unroll
  for (int j = 0; j < 4; j++) {
    int cc = c0 + 4 * cr + j;
    if (cc < NCLS) {
      float bias = b_fc[cc];
#pragma unroll
      for (int i = 0; i < 4; i++)
        out[(size_t)(r0 + 4 * rr + i) * NCLS + cc] = acc[i][j] + bias;
    }
  }
}

extern "C" void kernel_launch(void* const* d_in, const int* in_sizes, int n_in,
                              void* d_out, int out_size, void* d_ws, size_t ws_size,
                              hipStream_t stream) {
  const int*   xx   = (const int*)d_in[0];
  const float* emb  = (const float*)d_in[1];
  const float* w_ih = (const float*)d_in[2];
  const float* w_hh = (const float*)d_in[3];
  const float* b_ih = (const float*)d_in[4];
  const float* b_hh = (const float*)d_in[5];
  const float* w_fc = (const float*)d_in[6];
  const float* b_fc = (const float*)d_in[7];
  float* out = (float*)d_out;

  const size_t pbytes = (size_t)VOCAB * G4 * sizeof(_Float16); // 51.5 MB
  const size_t palign = (pbytes + 255) & ~(size_t)255;
  const size_t hbytes = (size_t)BATCH * HID * sizeof(float);

  float* hout;
  if (ws_size >= palign + hbytes) {
    _Float16* P = (_Float16*)d_ws;
    hout = (float*)((char*)d_ws + palign);
    build_P<<<(VOCAB + VROWS - 1) / VROWS, 512, 0, stream>>>(emb, w_ih, b_ih, b_hh, P);
    lstm_scan<true><<<BATCH, 256, 0, stream>>>(xx, emb, w_ih, w_hh, b_ih, b_hh, P, hout);
  } else {
    hout = (float*)d_ws;
    lstm_scan<false><<<BATCH, 256, 0, stream>>>(xx, emb, w_ih, w_hh, b_ih, b_hh,
                                                (const _Float16*)nullptr, hout);
  }
  dim3 fcg((NCLS + FCC - 1) / FCC, BATCH / FCR);
  fc_kernel<<<fcg, 256, 0, stream>>>(hout, w_fc, b_fc, out);
}